// Round 6
// baseline (137.910 us; speedup 1.0000x reference)
//
#include <hip/hip_runtime.h>
#include <hip/hip_bf16.h>

#define EPS 1e-5f

typedef float f32x4 __attribute__((ext_vector_type(4)));
typedef short s16x8 __attribute__((ext_vector_type(8)));

union FragU { uint4 u; s16x8 s; };

// clamp via single v_med3_f32
__device__ __forceinline__ float ht(float x){ return __builtin_amdgcn_fmed3f(x, -1.f, 1.f); }
__device__ __forceinline__ float sgn(float v){ return (v>0.f)?1.f:((v<0.f)?-1.f:0.f); }
__device__ __forceinline__ unsigned short f2bf(float f){
    unsigned int u = __builtin_bit_cast(unsigned int, f);
    u += 0x7FFFu + ((u>>16)&1u);                 // RNE to bf16
    return (unsigned short)(u>>16);
}
// packed pair f32x2 -> bf16x2 (v_cvt_pk_bf16_f32 on gfx950; RNE either way).
__device__ __forceinline__ unsigned pkbf(float a, float b){
    __hip_bfloat162 h = __float22bfloat162_rn(float2{a, b});
    unsigned u;
    __builtin_memcpy(&u, &h, sizeof(u));
    return u;
}

// =============== prep (6 blocks): A-fragments + BN params ===============
__global__ __launch_bounds__(512) void prep(
    const float* __restrict__ w1, const float* __restrict__ w2, const float* __restrict__ w3,
    const float* g1,const float* b1,const float* m1,const float* v1,
    const float* g2,const float* b2,const float* m2,const float* v2,
    const float* g3,const float* b3,const float* m3,const float* v3,
    unsigned short* __restrict__ a1, unsigned short* __restrict__ a2,
    unsigned short* __restrict__ a3, float* __restrict__ bn){
  const int t = threadIdx.x, bid = blockIdx.x;
  if(bid == 0){
    if(t < 64){                                  // conv1: K=32 (k<17 real)
      int q = t>>4, m = t&15;
      #pragma unroll
      for(int j=0;j<8;++j){ int k = 8*q+j;
        a1[t*8+j] = f2bf((k<17)? w1[m*17+k] : 0.f); }
    }
    if(t<16){ float s = g1[t]*rsqrtf(v1[t]+EPS); bn[t]    = s; bn[16+t]  = b1[t]-m1[t]*s; }
    if(t<32){ float s = g2[t]*rsqrtf(v2[t]+EPS); bn[32+t] = s; bn[64+t]  = b2[t]-m2[t]*s; }
    if(t<64){ float s = g3[t]*rsqrtf(v3[t]+EPS); bn[96+t] = s; bn[160+t] = b3[t]-m3[t]*s; }
  } else if(bid <= 2){                           // conv2: [h2][c5][q4][m16], k-major K=160
    int e = (bid-1)*512 + t;
    if(e < 640){
      int m = e&15, q = (e>>4)&3, hc = e>>6, c = hc%5, h = hc/5;
      int oc = m + 16*h, k = 2*c + (q>>1);
      #pragma unroll
      for(int j=0;j<8;++j){ int ic = 8*(q&1)+j;
        a2[e*8+j] = f2bf((k<9)? sgn(w2[(oc*16+ic)*9+k]) : 0.f); }
    }
  } else {                                       // conv3: [g4][c5][q4][m16], K=160
    int e = (bid-3)*512 + t;
    if(e < 1280){
      int m = e&15, q = (e>>4)&3, gc = e>>6, c = gc%5, g = gc/5;
      int oc = m + 16*g;
      #pragma unroll
      for(int j=0;j<8;++j){ int ic = 8*q+j;
        a3[e*8+j] = f2bf(sgn(w3[(oc*32+ic)*5+c])); }
    }
  }
}

// =============== fused: x -> conv1 -> conv2 -> conv3 -> partial feature sums ===========
// Block owns 16 final pooled positions [Q0,Q0+16), Q0 = 16*(blockIdx&15). Grid = 256*16.
// 256 threads (4 waves), ~22 KB LDS, launch_bounds(256,4): VGPR cap 128, 4 blocks/CU.
// Stage 1 loads its X-fragment DIRECTLY from global (swapped-operand layout makes the
// fragment 8 contiguous floats per lane): no xs staging, no barrier #1, loads pipeline
// under MFMAs. Zero-pad handled exactly at float2 granularity (parity: never straddles).
// NOTE (round-3 lesson): do NOT tighten launch_bounds below 128 VGPR (spills through
// scratch, 10x) and do NOT use agent-scope fences per block (per-XCD L2 writeback, 4096x).
__global__ __launch_bounds__(256, 4) void kfused(const float* __restrict__ x,
    const unsigned short* __restrict__ a1, const unsigned short* __restrict__ a2,
    const unsigned short* __restrict__ a3, const float* __restrict__ bn,
    float* __restrict__ partial){
  __shared__ __align__(16) unsigned short s1[296*26];    // [p1 local][16 oc], pad 26
  __shared__ __align__(16) unsigned short s2[68*42];     // [p2 local][32 oc], pad 42
  __shared__ float fws[4*32];
  const int b  = blockIdx.x >> 4;
  const int t  = blockIdx.x & 15;
  const int Q0 = 16*t;
  const int tid = threadIdx.x;
  const int m = tid & 15, q = (tid & 63) >> 4, w = tid >> 6;
  const float* xrow = &x[b*16384];

  FragU af1; af1.u = *(const uint4*)&a1[(q*16+m)*8];
  const float sc1 = bn[m], sh1 = bn[16+m];

  // ---- stage 1: conv1 on 592 pre-pool columns (37 tiles) -> s1[296][16] ----
  // lane (m,q) of tile needs floats xrow[x0+32*tile+2m+8q .. +7]; guard only needed for
  // edge blocks (t=0 low pad, t=15 high pad): block-uniform fast path for 14/16 blocks.
  const int x0 = 64*Q0 - 56;
  const bool safe = (x0 >= 0) && (x0 <= 15170);  // max lane idx x0+1213+7 <= 16383
  const int gbase = x0 + 2*m + 8*q;
  #pragma unroll 2
  for(int it = 0; it < 10; ++it){
    int tile = it*4 + w;                         // wave-uniform guard
    if(tile < 37){
      int g = gbase + 32*tile;
      float2 f0, f1, f2, f3;
      if(safe){
        f0 = *(const float2*)&xrow[g];
        f1 = *(const float2*)&xrow[g+2];
        f2 = *(const float2*)&xrow[g+4];
        f3 = *(const float2*)&xrow[g+6];
      } else {
        f0 = f1 = f2 = f3 = make_float2(0.f, 0.f);
        if((unsigned)g     <= 16382u) f0 = *(const float2*)&xrow[g];
        if((unsigned)(g+2) <= 16382u) f1 = *(const float2*)&xrow[g+2];
        if((unsigned)(g+4) <= 16382u) f2 = *(const float2*)&xrow[g+4];
        if((unsigned)(g+6) <= 16382u) f3 = *(const float2*)&xrow[g+6];
      }
      FragU bf;
      bf.u.x = pkbf(f0.x, f0.y);
      bf.u.y = pkbf(f1.x, f1.y);
      bf.u.z = pkbf(f2.x, f2.y);
      bf.u.w = pkbf(f3.x, f3.y);
      f32x4 acc = {0.f,0.f,0.f,0.f};
      acc = __builtin_amdgcn_mfma_f32_16x16x32_bf16(bf.s, af1.s, acc, 0,0,0);
      // lane holds spatial tile*16+4q+r for oc=m
      float v0 = ht(acc[0]*sc1 + sh1);
      float v1 = ht(acc[1]*sc1 + sh1);
      float v2 = ht(acc[2]*sc1 + sh1);
      float v3 = ht(acc[3]*sc1 + sh1);
      int ppl = tile*8 + 2*q;
      int gp  = 16*Q0 - 12 + ppl;
      float p0 = ((unsigned)gp     < 4096u) ? fmaxf(v0, v1) : 0.f;   // reference zero-pad
      float p1 = ((unsigned)(gp+1) < 4096u) ? fmaxf(v2, v3) : 0.f;
      unsigned u = pkbf(p0, p1);
      s1[ppl*26 + m]     = (unsigned short)u;
      s1[(ppl+1)*26 + m] = (unsigned short)(u >> 16);
    }
  }
  __syncthreads();

  // ---- stage 2: conv2 on 144 pre-pool columns (9 tiles) -> s2[68][32] ----
  FragU af2[2][5];
  #pragma unroll
  for(int h=0;h<2;++h)
    #pragma unroll
    for(int c=0;c<5;++c)
      af2[h][c].u = *(const uint4*)&a2[(((h*5+c)*4+q)*16+m)*8];
  float sc2[2], sh2[2];
  #pragma unroll
  for(int h=0;h<2;++h){
    sc2[h] = bn[32 + m + 16*h];
    sh2[h] = bn[64 + m + 16*h];
  }
  #pragma unroll
  for(int it = 0; it < 3; ++it){
    int tile = it*4 + w;                         // wave-uniform guard
    if(tile < 9){
      int nl = tile*16 + m;
      f32x4 acc[2] = {{0.f,0.f,0.f,0.f},{0.f,0.f,0.f,0.f}};
      #pragma unroll
      for(int c=0;c<5;++c){
        int row = 2*nl + 2*c + (q>>1);           // row <= 295 < 296
        FragU bf; bf.u = *(const uint4*)&s1[row*26 + 8*(q&1)];
        acc[0] = __builtin_amdgcn_mfma_f32_16x16x32_bf16(bf.s, af2[0][c].s, acc[0],0,0,0);
        acc[1] = __builtin_amdgcn_mfma_f32_16x16x32_bf16(bf.s, af2[1][c].s, acc[1],0,0,0);
      }
      int ppl = tile*8 + 2*q;
      int gp  = 4*Q0 - 2 + ppl;
      bool ok0 = (unsigned)gp     < 1024u;
      bool ok1 = (unsigned)(gp+1) < 1024u;
      #pragma unroll
      for(int h=0;h<2;++h){
        float v0 = ht(acc[h][0]*sc2[h] + sh2[h]);
        float v1 = ht(acc[h][1]*sc2[h] + sh2[h]);
        float v2 = ht(acc[h][2]*sc2[h] + sh2[h]);
        float v3 = ht(acc[h][3]*sc2[h] + sh2[h]);
        float p0 = ok0 ? fmaxf(v0, v1) : 0.f;
        float p1 = ok1 ? fmaxf(v2, v3) : 0.f;
        unsigned u = pkbf(p0, p1);
        if(ppl < 68){                            // ppl even -> covers ppl+1 too
          s2[ppl*42 + m + 16*h]     = (unsigned short)u;
          s2[(ppl+1)*42 + m + 16*h] = (unsigned short)(u >> 16);
        }
      }
    }
  }
  __syncthreads();

  // ---- stage 3: conv3 on 32 pre-pool columns; wave = (tile tw=w&1, oc-half gw=w>>1) ----
  const int tw = w & 1, gw = w >> 1;
  FragU af3[2][5];
  #pragma unroll
  for(int gl=0;gl<2;++gl)
    #pragma unroll
    for(int c=0;c<5;++c)
      af3[gl][c].u = *(const uint4*)&a3[((((2*gw+gl)*5+c)*4+q)*16+m)*8];
  float sc3[2], sh3[2];
  #pragma unroll
  for(int gl=0;gl<2;++gl){
    sc3[gl] = bn[96  + m + 16*(2*gw+gl)];
    sh3[gl] = bn[160 + m + 16*(2*gw+gl)];
  }
  {
    int nl = tw*16 + m;
    f32x4 acc[2] = {{0.f,0.f,0.f,0.f},{0.f,0.f,0.f,0.f}};
    #pragma unroll
    for(int c=0;c<5;++c){
      int row = 2*nl + c;                        // row <= 66 < 68
      FragU bf; bf.u = *(const uint4*)&s2[row*42 + 8*q];
      acc[0] = __builtin_amdgcn_mfma_f32_16x16x32_bf16(bf.s, af3[0][c].s, acc[0],0,0,0);
      acc[1] = __builtin_amdgcn_mfma_f32_16x16x32_bf16(bf.s, af3[1][c].s, acc[1],0,0,0);
    }
    #pragma unroll
    for(int gl=0;gl<2;++gl){
      float v0 = ht(acc[gl][0]*sc3[gl] + sh3[gl]);
      float v1 = ht(acc[gl][1]*sc3[gl] + sh3[gl]);
      float v2 = ht(acc[gl][2]*sc3[gl] + sh3[gl]);
      float v3 = ht(acc[gl][3]*sc3[gl] + sh3[gl]);
      // all 32 conv3 columns are valid (no guard needed); pool + feature partial-sum
      float sm = fmaxf(v0, v1) + fmaxf(v2, v3);
      sm += __shfl_xor(sm, 16);                  // reduce over q (spatial quarters)
      sm += __shfl_xor(sm, 32);
      if(q == 0) fws[w*32 + 16*gl + m] = sm;
    }
  }
  __syncthreads();
  if(tid < 64){
    int ocl = tid & 31, g = tid >> 5;            // oc = ocl + 32*g = tid
    float sum = fws[(2*g)*32 + ocl] + fws[(2*g+1)*32 + ocl];   // two tw waves per gw
    partial[(b*16 + t)*64 + tid] = sum;
  }
}

// =============== kfc: reduce partials + fc1 + ht + fc2 -> out[B,2] ======================
// 64 blocks x 256 threads; each 64-thread group handles one batch (4 batches/block).
__global__ __launch_bounds__(256) void kfc(const float* __restrict__ partial,
    const float* __restrict__ rms, const float* __restrict__ fc1w,
    const float* __restrict__ fc1b, const float* __restrict__ fc2w,
    const float* __restrict__ fc2b, float* __restrict__ out){
  __shared__ float feat[4][64];
  __shared__ float hbuf[4][32];
  const int tid = threadIdx.x;
  const int gr = tid >> 6, lt = tid & 63;        // group 0..3, lane-in-group 0..63
  const int b = blockIdx.x*4 + gr;
  float s = 0.f;
  #pragma unroll
  for(int t = 0; t < 16; ++t) s += partial[(b*16 + t)*64 + lt];
  feat[gr][lt] = s * (1.f/256.f);
  __syncthreads();
  if(lt < 32){
    float acc = fc1b[lt];
    const float* wv = &fc1w[lt*65];
    #pragma unroll
    for(int c = 0; c < 64; ++c) acc += wv[c]*feat[gr][c];
    acc += wv[64]*rms[b];
    hbuf[gr][lt] = ht(acc);
  }
  __syncthreads();
  if(lt < 2){
    float acc = fc2b[lt];
    const float* wv = &fc2w[lt*32];
    #pragma unroll
    for(int j = 0; j < 32; ++j) acc += wv[j]*hbuf[gr][j];
    out[b*2 + lt] = acc;
  }
}

extern "C" void kernel_launch(void* const* d_in, const int* in_sizes, int n_in,
                              void* d_out, int out_size, void* d_ws, size_t ws_size,
                              hipStream_t stream){
  (void)in_sizes; (void)n_in; (void)out_size; (void)ws_size;
  const float* x    = (const float*)d_in[0];
  const float* rms  = (const float*)d_in[1];
  const float* w1   = (const float*)d_in[2];
  const float* g1   = (const float*)d_in[3];
  const float* b1   = (const float*)d_in[4];
  const float* m1   = (const float*)d_in[5];
  const float* v1   = (const float*)d_in[6];
  const float* w2   = (const float*)d_in[7];
  const float* g2   = (const float*)d_in[8];
  const float* b2   = (const float*)d_in[9];
  const float* m2   = (const float*)d_in[10];
  const float* v2   = (const float*)d_in[11];
  const float* w3   = (const float*)d_in[12];
  const float* g3   = (const float*)d_in[13];
  const float* b3   = (const float*)d_in[14];
  const float* m3   = (const float*)d_in[15];
  const float* v3   = (const float*)d_in[16];
  const float* fc1w = (const float*)d_in[17];
  const float* fc1b = (const float*)d_in[18];
  const float* fc2w = (const float*)d_in[19];
  const float* fc2b = (const float*)d_in[20];
  float* out  = (float*)d_out;

  // ws layout
  float*          partial = (float*)d_ws;                      // 256*16*64 f32 (1 MB)
  unsigned short* a1  = (unsigned short*)(partial + 262144);   //   512 bf16
  unsigned short* a2  = a1 + 512;                              //  5120 bf16
  unsigned short* a3  = a2 + 5120;                             // 10240 bf16
  float*          bnp = (float*)(a3 + 10240);                  //   224 f32 (16B aligned)

  prep<<<6,    512, 0, stream>>>(w1, w2, w3, g1,b1,m1,v1, g2,b2,m2,v2, g3,b3,m3,v3,
                                 a1, a2, a3, bnp);
  kfused<<<4096, 256, 0, stream>>>(x, a1, a2, a3, bnp, partial);
  kfc<<<64, 256, 0, stream>>>(partial, rms, fc1w, fc1b, fc2w, fc2b, out);
}

// Round 7
// 122.224 us; speedup vs baseline: 1.1283x; 1.1283x over previous
//
#include <hip/hip_runtime.h>
#include <hip/hip_bf16.h>

#define EPS 1e-5f

typedef float f32x4 __attribute__((ext_vector_type(4)));
typedef short s16x8 __attribute__((ext_vector_type(8)));

union FragU { uint4 u; s16x8 s; };

// clamp via single v_med3_f32
__device__ __forceinline__ float ht(float x){ return __builtin_amdgcn_fmed3f(x, -1.f, 1.f); }
__device__ __forceinline__ float sgn(float v){ return (v>0.f)?1.f:((v<0.f)?-1.f:0.f); }
__device__ __forceinline__ unsigned short f2bf(float f){
    unsigned int u = __builtin_bit_cast(unsigned int, f);
    u += 0x7FFFu + ((u>>16)&1u);                 // RNE to bf16
    return (unsigned short)(u>>16);
}
// packed pair f32x2 -> bf16x2 (v_cvt_pk_bf16_f32 on gfx950; RNE either way).
__device__ __forceinline__ unsigned pkbf(float a, float b){
    __hip_bfloat162 h = __float22bfloat162_rn(float2{a, b});
    unsigned u;
    __builtin_memcpy(&u, &h, sizeof(u));
    return u;
}

// =============== prep (6 blocks): A-fragments + BN params ===============
__global__ __launch_bounds__(512) void prep(
    const float* __restrict__ w1, const float* __restrict__ w2, const float* __restrict__ w3,
    const float* g1,const float* b1,const float* m1,const float* v1,
    const float* g2,const float* b2,const float* m2,const float* v2,
    const float* g3,const float* b3,const float* m3,const float* v3,
    unsigned short* __restrict__ a1, unsigned short* __restrict__ a2,
    unsigned short* __restrict__ a3, float* __restrict__ bn){
  const int t = threadIdx.x, bid = blockIdx.x;
  if(bid == 0){
    if(t < 64){                                  // conv1: K=32 (k<17 real)
      int q = t>>4, m = t&15;
      #pragma unroll
      for(int j=0;j<8;++j){ int k = 8*q+j;
        a1[t*8+j] = f2bf((k<17)? w1[m*17+k] : 0.f); }
    }
    if(t<16){ float s = g1[t]*rsqrtf(v1[t]+EPS); bn[t]    = s; bn[16+t]  = b1[t]-m1[t]*s; }
    if(t<32){ float s = g2[t]*rsqrtf(v2[t]+EPS); bn[32+t] = s; bn[64+t]  = b2[t]-m2[t]*s; }
    if(t<64){ float s = g3[t]*rsqrtf(v3[t]+EPS); bn[96+t] = s; bn[160+t] = b3[t]-m3[t]*s; }
  } else if(bid <= 2){                           // conv2: [h2][c5][q4][m16], k-major K=160
    int e = (bid-1)*512 + t;
    if(e < 640){
      int m = e&15, q = (e>>4)&3, hc = e>>6, c = hc%5, h = hc/5;
      int oc = m + 16*h, k = 2*c + (q>>1);
      #pragma unroll
      for(int j=0;j<8;++j){ int ic = 8*(q&1)+j;
        a2[e*8+j] = f2bf((k<9)? sgn(w2[(oc*16+ic)*9+k]) : 0.f); }
    }
  } else {                                       // conv3: [g4][c5][q4][m16], K=160
    int e = (bid-3)*512 + t;
    if(e < 1280){
      int m = e&15, q = (e>>4)&3, gc = e>>6, c = gc%5, g = gc/5;
      int oc = m + 16*g;
      #pragma unroll
      for(int j=0;j<8;++j){ int ic = 8*q+j;
        a3[e*8+j] = f2bf(sgn(w3[(oc*32+ic)*5+c])); }
    }
  }
}

// =============== fused: x -> conv1 -> conv2 -> conv3 -> partial feature sums ===========
// Block owns 16 final pooled positions [Q0,Q0+16), Q0 = 16*(blockIdx&15). Grid = 256*16.
// 256 threads (4 waves), ~22 KB LDS, launch_bounds(256,4): VGPR cap 128, 4 blocks/CU.
// MFMA operands SWAPPED vs classic layout: mfma(X, W) => D[spatial][oc], so the
// 4 acc regs are 4 consecutive spatial positions for oc = lane&15: maxpool is
// 2 in-register fmaxf (no DPP), BN params are per-lane scalars.
// Session lessons: (R3) no launch_bounds below 128 VGPR (scratch spills, 10x); no
// agent-scope fence per block (per-XCD L2 writeback, 4096x). (R6) keep the xs LDS
// staging: direct-global fragment gathers re-fetch x ~5x through the VMEM pipe and
// cost more than the staging barrier. (R4/R5) pads, unrolls, round-count: all noise.
__global__ __launch_bounds__(256, 4) void kfused(const float* __restrict__ x,
    const unsigned short* __restrict__ a1, const unsigned short* __restrict__ a2,
    const unsigned short* __restrict__ a3, const float* __restrict__ bn,
    float* __restrict__ partial){
  __shared__ __align__(16) unsigned short xs[1216];      // x[x0 .. x0+1216) bf16
  __shared__ __align__(16) unsigned short s1[296*24];    // [p1 local][16 oc], pad 24
  __shared__ __align__(16) unsigned short s2[68*40];     // [p2 local][32 oc], pad 40
  __shared__ float fws[4*32];
  const int b  = blockIdx.x >> 4;
  const int t  = blockIdx.x & 15;
  const int Q0 = 16*t;
  const int tid = threadIdx.x;
  const int m = tid & 15, q = (tid & 63) >> 4, w = tid >> 6;

  // ---- stage x -> xs (304 float4 = 1216 elems) ----
  const int x0 = 64*Q0 - 56;
  const float* xrow = &x[b*16384];
  for(int i = tid; i < 304; i += 256){
    int g0 = x0 + 4*i;
    float4 v = make_float4(0.f,0.f,0.f,0.f);
    if(g0 >= 0 && g0 <= 16380) v = *(const float4*)&xrow[g0];
    uint2 pk;
    pk.x = pkbf(v.x, v.y);
    pk.y = pkbf(v.z, v.w);
    *(uint2*)&xs[4*i] = pk;
  }
  FragU af1; af1.u = *(const uint4*)&a1[(q*16+m)*8];
  const float sc1 = bn[m], sh1 = bn[16+m];
  __syncthreads();

  // ---- stage 1: conv1 on 592 pre-pool columns (37 tiles) -> s1[296][16] ----
  const unsigned* X32 = (const unsigned*)xs;
  for(int it = 0; it < 10; ++it){
    int tile = it*4 + w;                         // wave-uniform guard
    if(tile < 37){
      int d = tile*16 + m + 4*q;                 // A[row=m][k=8q+j] = xs[2*(tile*16+m)+k]
      FragU bf;
      bf.u.x = X32[d]; bf.u.y = X32[d+1]; bf.u.z = X32[d+2]; bf.u.w = X32[d+3];
      f32x4 acc = {0.f,0.f,0.f,0.f};
      acc = __builtin_amdgcn_mfma_f32_16x16x32_bf16(bf.s, af1.s, acc, 0,0,0);
      // lane holds spatial tile*16+4q+r for oc=m
      float v0 = ht(acc[0]*sc1 + sh1);
      float v1 = ht(acc[1]*sc1 + sh1);
      float v2 = ht(acc[2]*sc1 + sh1);
      float v3 = ht(acc[3]*sc1 + sh1);
      int ppl = tile*8 + 2*q;
      int gp  = 16*Q0 - 12 + ppl;
      float p0 = ((unsigned)gp     < 4096u) ? fmaxf(v0, v1) : 0.f;   // reference zero-pad
      float p1 = ((unsigned)(gp+1) < 4096u) ? fmaxf(v2, v3) : 0.f;
      unsigned u = pkbf(p0, p1);
      s1[ppl*24 + m]     = (unsigned short)u;
      s1[(ppl+1)*24 + m] = (unsigned short)(u >> 16);
    }
  }
  __syncthreads();

  // ---- stage 2: conv2 on 144 pre-pool columns (9 tiles) -> s2[68][32] ----
  FragU af2[2][5];
  #pragma unroll
  for(int h=0;h<2;++h)
    #pragma unroll
    for(int c=0;c<5;++c)
      af2[h][c].u = *(const uint4*)&a2[(((h*5+c)*4+q)*16+m)*8];
  float sc2[2], sh2[2];
  #pragma unroll
  for(int h=0;h<2;++h){
    sc2[h] = bn[32 + m + 16*h];
    sh2[h] = bn[64 + m + 16*h];
  }
  for(int it = 0; it < 3; ++it){
    int tile = it*4 + w;                         // wave-uniform guard
    if(tile < 9){
      int nl = tile*16 + m;
      f32x4 acc[2] = {{0.f,0.f,0.f,0.f},{0.f,0.f,0.f,0.f}};
      #pragma unroll
      for(int c=0;c<5;++c){
        int row = 2*nl + 2*c + (q>>1);           // row <= 295 < 296
        FragU bf; bf.u = *(const uint4*)&s1[row*24 + 8*(q&1)];
        acc[0] = __builtin_amdgcn_mfma_f32_16x16x32_bf16(bf.s, af2[0][c].s, acc[0],0,0,0);
        acc[1] = __builtin_amdgcn_mfma_f32_16x16x32_bf16(bf.s, af2[1][c].s, acc[1],0,0,0);
      }
      int ppl = tile*8 + 2*q;
      int gp  = 4*Q0 - 2 + ppl;
      bool ok0 = (unsigned)gp     < 1024u;
      bool ok1 = (unsigned)(gp+1) < 1024u;
      #pragma unroll
      for(int h=0;h<2;++h){
        float v0 = ht(acc[h][0]*sc2[h] + sh2[h]);
        float v1 = ht(acc[h][1]*sc2[h] + sh2[h]);
        float v2 = ht(acc[h][2]*sc2[h] + sh2[h]);
        float v3 = ht(acc[h][3]*sc2[h] + sh2[h]);
        float p0 = ok0 ? fmaxf(v0, v1) : 0.f;
        float p1 = ok1 ? fmaxf(v2, v3) : 0.f;
        unsigned u = pkbf(p0, p1);
        if(ppl < 68){                            // ppl even -> covers ppl+1 too
          s2[ppl*40 + m + 16*h]     = (unsigned short)u;
          s2[(ppl+1)*40 + m + 16*h] = (unsigned short)(u >> 16);
        }
      }
    }
  }
  __syncthreads();

  // ---- stage 3: conv3 on 32 pre-pool columns; wave = (tile tw=w&1, oc-half gw=w>>1) ----
  const int tw = w & 1, gw = w >> 1;
  FragU af3[2][5];
  #pragma unroll
  for(int gl=0;gl<2;++gl)
    #pragma unroll
    for(int c=0;c<5;++c)
      af3[gl][c].u = *(const uint4*)&a3[((((2*gw+gl)*5+c)*4+q)*16+m)*8];
  float sc3[2], sh3[2];
  #pragma unroll
  for(int gl=0;gl<2;++gl){
    sc3[gl] = bn[96  + m + 16*(2*gw+gl)];
    sh3[gl] = bn[160 + m + 16*(2*gw+gl)];
  }
  {
    int nl = tw*16 + m;
    f32x4 acc[2] = {{0.f,0.f,0.f,0.f},{0.f,0.f,0.f,0.f}};
    #pragma unroll
    for(int c=0;c<5;++c){
      int row = 2*nl + c;                        // row <= 66 < 68
      FragU bf; bf.u = *(const uint4*)&s2[row*40 + 8*q];
      acc[0] = __builtin_amdgcn_mfma_f32_16x16x32_bf16(bf.s, af3[0][c].s, acc[0],0,0,0);
      acc[1] = __builtin_amdgcn_mfma_f32_16x16x32_bf16(bf.s, af3[1][c].s, acc[1],0,0,0);
    }
    #pragma unroll
    for(int gl=0;gl<2;++gl){
      float v0 = ht(acc[gl][0]*sc3[gl] + sh3[gl]);
      float v1 = ht(acc[gl][1]*sc3[gl] + sh3[gl]);
      float v2 = ht(acc[gl][2]*sc3[gl] + sh3[gl]);
      float v3 = ht(acc[gl][3]*sc3[gl] + sh3[gl]);
      // all 32 conv3 columns are valid (no guard needed); pool + feature partial-sum
      float sm = fmaxf(v0, v1) + fmaxf(v2, v3);
      sm += __shfl_xor(sm, 16);                  // reduce over q (spatial quarters)
      sm += __shfl_xor(sm, 32);
      if(q == 0) fws[w*32 + 16*gl + m] = sm;
    }
  }
  __syncthreads();
  if(tid < 64){
    int ocl = tid & 31, g = tid >> 5;            // oc = ocl + 32*g = tid
    float sum = fws[(2*g)*32 + ocl] + fws[(2*g+1)*32 + ocl];   // two tw waves per gw
    partial[(b*16 + t)*64 + tid] = sum;
  }
}

// =============== kfc: reduce partials + fc1 + ht + fc2 -> out[B,2] ======================
__global__ __launch_bounds__(64) void kfc(const float* __restrict__ partial,
    const float* __restrict__ rms, const float* __restrict__ fc1w,
    const float* __restrict__ fc1b, const float* __restrict__ fc2w,
    const float* __restrict__ fc2b, float* __restrict__ out){
  __shared__ float feat[64];
  __shared__ float hbuf[32];
  const int b = blockIdx.x, tid = threadIdx.x;
  float s = 0.f;
  #pragma unroll
  for(int t = 0; t < 16; ++t) s += partial[(b*16 + t)*64 + tid];
  feat[tid] = s * (1.f/256.f);
  __syncthreads();
  if(tid < 32){
    float acc = fc1b[tid];
    const float* wv = &fc1w[tid*65];
    #pragma unroll
    for(int c = 0; c < 64; ++c) acc += wv[c]*feat[c];
    acc += wv[64]*rms[b];
    hbuf[tid] = ht(acc);
  }
  __syncthreads();
  if(tid < 2){
    float acc = fc2b[tid];
    const float* wv = &fc2w[tid*32];
    #pragma unroll
    for(int j = 0; j < 32; ++j) acc += wv[j]*hbuf[j];
    out[b*2 + tid] = acc;
  }
}

extern "C" void kernel_launch(void* const* d_in, const int* in_sizes, int n_in,
                              void* d_out, int out_size, void* d_ws, size_t ws_size,
                              hipStream_t stream){
  (void)in_sizes; (void)n_in; (void)out_size; (void)ws_size;
  const float* x    = (const float*)d_in[0];
  const float* rms  = (const float*)d_in[1];
  const float* w1   = (const float*)d_in[2];
  const float* g1   = (const float*)d_in[3];
  const float* b1   = (const float*)d_in[4];
  const float* m1   = (const float*)d_in[5];
  const float* v1   = (const float*)d_in[6];
  const float* w2   = (const float*)d_in[7];
  const float* g2   = (const float*)d_in[8];
  const float* b2   = (const float*)d_in[9];
  const float* m2   = (const float*)d_in[10];
  const float* v2   = (const float*)d_in[11];
  const float* w3   = (const float*)d_in[12];
  const float* g3   = (const float*)d_in[13];
  const float* b3   = (const float*)d_in[14];
  const float* m3   = (const float*)d_in[15];
  const float* v3   = (const float*)d_in[16];
  const float* fc1w = (const float*)d_in[17];
  const float* fc1b = (const float*)d_in[18];
  const float* fc2w = (const float*)d_in[19];
  const float* fc2b = (const float*)d_in[20];
  float* out  = (float*)d_out;

  // ws layout
  float*          partial = (float*)d_ws;                      // 256*16*64 f32 (1 MB)
  unsigned short* a1  = (unsigned short*)(partial + 262144);   //   512 bf16
  unsigned short* a2  = a1 + 512;                              //  5120 bf16
  unsigned short* a3  = a2 + 5120;                             // 10240 bf16
  float*          bnp = (float*)(a3 + 10240);                  //   224 f32 (16B aligned)

  prep<<<6,    512, 0, stream>>>(w1, w2, w3, g1,b1,m1,v1, g2,b2,m2,v2, g3,b3,m3,v3,
                                 a1, a2, a3, bnp);
  kfused<<<4096, 256, 0, stream>>>(x, a1, a2, a3, bnp, partial);
  kfc<<<256, 64, 0, stream>>>(partial, rms, fc1w, fc1b, fc2w, fc2b, out);
}